// Round 1
// baseline (2906.873 us; speedup 1.0000x reference)
//
#include <hip/hip_runtime.h>
#include <hip/hip_bf16.h>

// Sizes (fixed by the problem)
#define BB 64
#define TT 2048
#define II 128
#define HH 256
#define GG 768   // 3*H

typedef _Float16 h2 __attribute__((ext_vector_type(2)));
union U32H2 { unsigned int u; h2 h; };

static __device__ __forceinline__ float fdot2f(unsigned int w, h2 hv, float acc){
#if __has_builtin(__builtin_amdgcn_fdot2)
    U32H2 c; c.u = w;
    return __builtin_amdgcn_fdot2(c.h, hv, acc, false);
#else
    U32H2 c; c.u = w;
    return acc + (float)c.h.x * (float)hv.x + (float)c.h.y * (float)hv.y;
#endif
}

// ---------------------------------------------------------------------------
// Phase 0: convert W_hh [768][256] f32 -> packed f16 pairs, transposed layout
// Wt[kk][g] = pack(W_hh[g][2kk], W_hh[g][2kk+1]),  kk in [0,128), g in [0,768)
// ---------------------------------------------------------------------------
__global__ void conv_whh(const float* __restrict__ Whh, unsigned int* __restrict__ Wt){
    int idx = blockIdx.x * 256 + threadIdx.x;   // 98304 total
    int kk = idx / GG;
    int g  = idx - kk * GG;
    float a = Whh[g * HH + 2*kk];
    float b = Whh[g * HH + 2*kk + 1];
    U32H2 c; c.h.x = (_Float16)a; c.h.y = (_Float16)b;
    Wt[idx] = c.u;
}

// ---------------------------------------------------------------------------
// Phase 1: gi[bt][g] = sum_k x[bt][k] * W_ih[g][k] + b_ih[g], stored as f16.
// Tile 128(bt) x 128(g), K=128 in one shot. LDS transposed [k][row].
// ---------------------------------------------------------------------------
__global__ __launch_bounds__(256) void gi_gemm(const float* __restrict__ x,
                                               const float* __restrict__ Wih,
                                               const float* __restrict__ bih,
                                               _Float16* __restrict__ gi){
    __shared__ float xs [128 * 132];   // [k][bt]
    __shared__ float wsh[128 * 132];   // [k][g]
    const int bt0 = blockIdx.x * 128;
    const int g0  = blockIdx.y * 128;
    const int tid = threadIdx.x;
    for (int i = tid; i < 128 * 128; i += 256){
        int r = i >> 7, c = i & 127;
        xs [c * 132 + r] = x  [(size_t)(bt0 + r) * II + c];
        wsh[c * 132 + r] = Wih[(size_t)(g0  + r) * II + c];
    }
    __syncthreads();
    const int ty = tid >> 4, tx = tid & 15;   // ty: bt octet, tx: g quad-pair
    float acc[8][8] = {};
    for (int k = 0; k < 128; ++k){
        const float4 a0 = *(const float4*)&xs [k * 132 + ty * 8];
        const float4 a1 = *(const float4*)&xs [k * 132 + ty * 8 + 4];
        const float4 b0 = *(const float4*)&wsh[k * 132 + tx * 4];
        const float4 b1 = *(const float4*)&wsh[k * 132 + tx * 4 + 64];
        const float av[8] = {a0.x,a0.y,a0.z,a0.w,a1.x,a1.y,a1.z,a1.w};
        const float bv[8] = {b0.x,b0.y,b0.z,b0.w,b1.x,b1.y,b1.z,b1.w};
        #pragma unroll
        for (int ii = 0; ii < 8; ++ii)
            #pragma unroll
            for (int jj = 0; jj < 8; ++jj)
                acc[ii][jj] += av[ii] * bv[jj];
    }
    #pragma unroll
    for (int ii = 0; ii < 8; ++ii){
        const int bt = bt0 + ty * 8 + ii;
        _Float16* gp = gi + (size_t)bt * GG + g0;
        #pragma unroll
        for (int jj = 0; jj < 8; ++jj){
            int gl = (jj < 4) ? (tx * 4 + jj) : (64 + tx * 4 + (jj - 4));
            gp[gl] = (_Float16)(acc[ii][jj] + bih[g0 + gl]);
        }
    }
}

// ---------------------------------------------------------------------------
// Phase 2: the recurrence. One block per batch element, 512 threads.
//   j = tid & 255 (hidden index), half = tid >> 8 (k-half of the matvec).
//   Each thread holds W_hh rows (j, j+256, j+512) for its k-half as 192
//   packed-f16-pair registers. h broadcast through LDS as f16 pairs.
// ---------------------------------------------------------------------------
__global__ __launch_bounds__(512, 2) void gru_rec(
        const unsigned int* __restrict__ Wt,   // [128][768] packed f16 pairs
        const _Float16* __restrict__ gi,       // [64][2048][768]
        const float* __restrict__ bhh,         // [768]
        float* __restrict__ hid)               // [64][2048][256]
{
    const int b    = blockIdx.x;
    const int tid  = threadIdx.x;
    const int j    = tid & 255;
    const int half = tid >> 8;

    unsigned int Wr[64], Wz[64], Wn[64];
    {
        const unsigned int* Wb = Wt + half * 64 * GG;
        #pragma unroll
        for (int m = 0; m < 64; ++m){
            Wr[m] = Wb[m * GG + j];
            Wz[m] = Wb[m * GG + j + 256];
            Wn[m] = Wb[m * GG + j + 512];
        }
    }
    float br = 0.f, bz = 0.f, bn = 0.f;
    if (half == 0){ br = bhh[j]; bz = bhh[j + 256]; bn = bhh[j + 512]; }

    __shared__ __align__(16) _Float16 hps[256];   // h as f16, read as packed pairs
    __shared__ float pr[256], pz[256], pn[256];   // half-1 partial sums
    if (tid < 256) hps[tid] = (_Float16)0.f;

    float h_prev = 0.f;
    const _Float16* gib = gi + (size_t)b * TT * GG;
    float* hob = hid + (size_t)b * TT * HH;
    __syncthreads();

    for (int t = 0; t < TT; ++t){
        // prefetch this step's input projection (needed only after the dots)
        float gir = 0.f, giz = 0.f, gin = 0.f;
        if (half == 0){
            const _Float16* g3 = gib + (size_t)t * GG + j;
            gir = (float)g3[0]; giz = (float)g3[256]; gin = (float)g3[512];
        }
        float ar = br, az = bz, an = bn;
        const uint4* hv = ((const uint4*)hps) + half * 16;
        #pragma unroll
        for (int mm = 0; mm < 16; ++mm){
            union { uint4 v; h2 p[4]; } hh;
            hh.v = hv[mm];
            #pragma unroll
            for (int q = 0; q < 4; ++q){
                ar = fdot2f(Wr[4*mm + q], hh.p[q], ar);
                az = fdot2f(Wz[4*mm + q], hh.p[q], az);
                an = fdot2f(Wn[4*mm + q], hh.p[q], an);
            }
        }
        if (half == 1){ pr[j] = ar; pz[j] = az; pn[j] = an; }
        __syncthreads();
        if (half == 0){
            float ghr = ar + pr[j];
            float ghz = az + pz[j];
            float ghn = an + pn[j];
            float r = 1.f / (1.f + __expf(-(gir + ghr)));
            float z = 1.f / (1.f + __expf(-(giz + ghz)));
            float tin = gin + r * ghn;
            tin = fminf(15.f, fmaxf(-15.f, tin));
            float e2 = __expf(2.f * tin);
            float n = (e2 - 1.f) / (e2 + 1.f);
            float hn = (1.f - z) * n + z * h_prev;
            h_prev = hn;
            hob[(size_t)t * HH + j] = hn;
            hps[j] = (_Float16)hn;
        }
        __syncthreads();
    }
}

// ---------------------------------------------------------------------------
// Phase 3: outputs[bt] = dot(hiddens[bt], W_o) + b_o.  One wave per bt.
// ---------------------------------------------------------------------------
__global__ __launch_bounds__(256) void out_proj(const float* __restrict__ hid,
                                                const float* __restrict__ Wo,
                                                const float* __restrict__ bo,
                                                float* __restrict__ outp){
    const int w = threadIdx.x >> 6, l = threadIdx.x & 63;
    const size_t bt = (size_t)blockIdx.x * 4 + w;
    const float4 hv = ((const float4*)(hid + bt * HH))[l];
    const float4 wv = ((const float4*)Wo)[l];
    float s = hv.x*wv.x + hv.y*wv.y + hv.z*wv.z + hv.w*wv.w;
    #pragma unroll
    for (int off = 32; off > 0; off >>= 1) s += __shfl_down(s, off, 64);
    if (l == 0) outp[bt] = s + bo[0];
}

// ---------------------------------------------------------------------------
extern "C" void kernel_launch(void* const* d_in, const int* in_sizes, int n_in,
                              void* d_out, int out_size, void* d_ws, size_t ws_size,
                              hipStream_t stream) {
    const float* x   = (const float*)d_in[0];
    const float* Wih = (const float*)d_in[1];
    const float* Whh = (const float*)d_in[2];
    const float* bih = (const float*)d_in[3];
    const float* bhh = (const float*)d_in[4];
    const float* Wo  = (const float*)d_in[5];
    const float* bo  = (const float*)d_in[6];

    float* outputs = (float*)d_out;                      // [64][2048][1]
    float* hiddens = (float*)d_out + (size_t)BB * TT;    // [64][2048][256]

    // Workspace layout: Wt (393216 B) | gi f16 (201326592 B)  => ~192.4 MiB
    unsigned int* Wt = (unsigned int*)d_ws;
    _Float16* gi = (_Float16*)((char*)d_ws + 128 * GG * sizeof(unsigned int));

    conv_whh<<<dim3(98304 / 256), dim3(256), 0, stream>>>(Whh, Wt);
    gi_gemm <<<dim3((BB * TT) / 128, GG / 128), dim3(256), 0, stream>>>(x, Wih, bih, gi);
    gru_rec <<<dim3(BB), dim3(512), 0, stream>>>(Wt, gi, bhh, hiddens);
    out_proj<<<dim3((BB * TT) / 4), dim3(256), 0, stream>>>(hiddens, Wo, bo, outputs);
}

// Round 3
// 2620.476 us; speedup vs baseline: 1.1093x; 1.1093x over previous
//
#include <hip/hip_runtime.h>
#include <hip/hip_bf16.h>

#define BB 64
#define TT 2048
#define II 128
#define HH 256
#define GG 768   // 3*H

typedef _Float16 h2 __attribute__((ext_vector_type(2)));
typedef _Float16 half8 __attribute__((ext_vector_type(8)));
typedef float f32x4 __attribute__((ext_vector_type(4)));
union U32H2 { unsigned int u; h2 h; };

static __device__ __forceinline__ float fdot2f(unsigned int w, h2 hv, float acc){
#if __has_builtin(__builtin_amdgcn_fdot2)
    U32H2 c; c.u = w;
    return __builtin_amdgcn_fdot2(c.h, hv, acc, false);
#else
    U32H2 c; c.u = w;
    return acc + (float)c.h.x * (float)hv.x + (float)c.h.y * (float)hv.y;
#endif
}

// ---------------------------------------------------------------------------
// Phase 0a: W_hh [768][256] f32 -> packed f16 pairs, transposed:
// Wt[kk][g] = pack(W_hh[g][2kk], W_hh[g][2kk+1]), kk in [0,128), g in [0,768)
// ---------------------------------------------------------------------------
__global__ void conv_whh(const float* __restrict__ Whh, unsigned int* __restrict__ Wt){
    int idx = blockIdx.x * 256 + threadIdx.x;   // 98304 total
    int kk = idx / GG;
    int g  = idx - kk * GG;
    float a = Whh[g * HH + 2*kk];
    float b = Whh[g * HH + 2*kk + 1];
    U32H2 c; c.h.x = (_Float16)a; c.h.y = (_Float16)b;
    Wt[idx] = c.u;
}

// Phase 0b: W_ih [768][128] f32 -> f16 (same layout)
__global__ void conv_wih(const float* __restrict__ Wih, _Float16* __restrict__ Wh){
    int idx = blockIdx.x * 256 + threadIdx.x;   // 98304 total
    Wh[idx] = (_Float16)Wih[idx];
}

// ---------------------------------------------------------------------------
// Phase 1: gi[bt][g] = sum_k x[bt][k]*W_ih[g][k] + b_ih[g]  via f16 MFMA.
// Block = 256 thr (4 waves). Each wave: M=16 rows, N=64 cols, K=128.
// A (x) converted fp32->f16 in-register; B from pre-converted Wh.
// ---------------------------------------------------------------------------
__global__ __launch_bounds__(256) void gi_mfma(const float* __restrict__ x,
                                               const _Float16* __restrict__ Wh,
                                               const float* __restrict__ bih,
                                               _Float16* __restrict__ gi){
    const int wave = threadIdx.x >> 6;
    const int lane = threadIdx.x & 63;
    const int l16  = lane & 15, q = lane >> 4;
    const int m    = blockIdx.x * 64 + wave * 16 + l16;   // bt row for A frag
    const int n0   = blockIdx.y * 64;                      // g col base
    f32x4 acc[4] = {};
    #pragma unroll
    for (int s = 0; s < 4; ++s){                           // K steps of 32
        const float* xp = x + (size_t)m * II + s*32 + q*8;
        float4 a0 = *(const float4*)xp;
        float4 a1 = *(const float4*)(xp + 4);
        half8 af = { (_Float16)a0.x,(_Float16)a0.y,(_Float16)a0.z,(_Float16)a0.w,
                     (_Float16)a1.x,(_Float16)a1.y,(_Float16)a1.z,(_Float16)a1.w };
        #pragma unroll
        for (int t = 0; t < 4; ++t){                       // N tiles of 16
            const _Float16* wp = Wh + (size_t)(n0 + t*16 + l16) * II + s*32 + q*8;
            half8 bf = *(const half8*)wp;
            acc[t] = __builtin_amdgcn_mfma_f32_16x16x32_f16(af, bf, acc[t], 0, 0, 0);
        }
    }
    // D layout: col = lane&15 (n), row = (lane>>4)*4 + reg (m)
    #pragma unroll
    for (int t = 0; t < 4; ++t){
        int n = n0 + t*16 + l16;
        float bv = bih[n];
        #pragma unroll
        for (int r = 0; r < 4; ++r){
            int row = blockIdx.x*64 + wave*16 + q*4 + r;
            gi[(size_t)row * GG + n] = (_Float16)(acc[t][r] + bv);
        }
    }
}

// ---------------------------------------------------------------------------
// Phase 2: recurrence. One block per batch element, 1024 threads (16 waves).
//   j = tid&255 (hidden out), q = tid>>8 (k-quarter: pairs [32q,32q+32)).
//   96 packed-f16-pair W regs per thread. Waves with q==0 own the gate math.
// ---------------------------------------------------------------------------
__global__ __launch_bounds__(1024) void gru_rec(
        const unsigned int* __restrict__ Wt,   // [128][768] packed f16 pairs
        const _Float16* __restrict__ gi,       // [64][2048][768]
        const float* __restrict__ bhh,         // [768]
        float* __restrict__ hid)               // [64][2048][256]
{
    const int b   = blockIdx.x;
    const int tid = threadIdx.x;
    const int j   = tid & 255;
    const int q   = tid >> 8;      // 0..3

    unsigned int Wr[32], Wz[32], Wn[32];
    {
        const unsigned int* Wb = Wt + q * 32 * GG;
        #pragma unroll
        for (int m = 0; m < 32; ++m){
            Wr[m] = Wb[m * GG + j];
            Wz[m] = Wb[m * GG + j + 256];
            Wn[m] = Wb[m * GG + j + 512];
        }
    }
    float br = 0.f, bz = 0.f, bn = 0.f;
    if (q == 0){ br = bhh[j]; bz = bhh[j + 256]; bn = bhh[j + 512]; }

    __shared__ __align__(16) _Float16 hps[256];   // h as f16 (read as uint4 broadcast)
    __shared__ float pbuf[3 * GG];                // [(q-1)][gate][j] partials
    if (tid < 256) hps[tid] = (_Float16)0.f;

    float h_prev = 0.f;
    const _Float16* gib = gi + (size_t)b * TT * GG;
    float* hob = hid + (size_t)b * TT * HH;
    __syncthreads();

    for (int t = 0; t < TT; ++t){
        float gir = 0.f, giz = 0.f, gin = 0.f;
        if (q == 0){
            const _Float16* g3 = gib + (size_t)t * GG + j;
            gir = (float)g3[0]; giz = (float)g3[256]; gin = (float)g3[512];
        }
        float ar = br, az = bz, an = bn;
        const uint4* hv = ((const uint4*)hps) + q * 8;   // wave-uniform -> LDS broadcast
        #pragma unroll
        for (int mm = 0; mm < 8; ++mm){
            union { uint4 v; h2 p[4]; } hh;
            hh.v = hv[mm];
            #pragma unroll
            for (int p = 0; p < 4; ++p){
                ar = fdot2f(Wr[4*mm + p], hh.p[p], ar);
                az = fdot2f(Wz[4*mm + p], hh.p[p], az);
                an = fdot2f(Wn[4*mm + p], hh.p[p], an);
            }
        }
        if (q){
            float* pb = pbuf + (q - 1) * GG;
            pb[j] = ar; pb[j + 256] = az; pb[j + 512] = an;
        }
        __syncthreads();
        if (q == 0){
            ar += pbuf[j]       + pbuf[GG + j]       + pbuf[2*GG + j];
            az += pbuf[j + 256] + pbuf[GG + j + 256] + pbuf[2*GG + j + 256];
            an += pbuf[j + 512] + pbuf[GG + j + 512] + pbuf[2*GG + j + 512];
            float r = 1.f / (1.f + __expf(-(gir + ar)));
            float z = 1.f / (1.f + __expf(-(giz + az)));
            float tin = gin + r * an;
            tin = fminf(15.f, fmaxf(-15.f, tin));
            float e2 = __expf(2.f * tin);
            float n = (e2 - 1.f) / (e2 + 1.f);
            float hn = (1.f - z) * n + z * h_prev;
            h_prev = hn;
            hob[(size_t)t * HH + j] = hn;
            hps[j] = (_Float16)hn;
        }
        __syncthreads();
    }
}

// ---------------------------------------------------------------------------
// Phase 3: outputs[bt] = dot(hiddens[bt], W_o) + b_o.  One wave per bt.
// ---------------------------------------------------------------------------
__global__ __launch_bounds__(256) void out_proj(const float* __restrict__ hid,
                                                const float* __restrict__ Wo,
                                                const float* __restrict__ bo,
                                                float* __restrict__ outp){
    const int w = threadIdx.x >> 6, l = threadIdx.x & 63;
    const size_t bt = (size_t)blockIdx.x * 4 + w;
    const float4 hv = ((const float4*)(hid + bt * HH))[l];
    const float4 wv = ((const float4*)Wo)[l];
    float s = hv.x*wv.x + hv.y*wv.y + hv.z*wv.z + hv.w*wv.w;
    #pragma unroll
    for (int off = 32; off > 0; off >>= 1) s += __shfl_down(s, off, 64);
    if (l == 0) outp[bt] = s + bo[0];
}

// ---------------------------------------------------------------------------
extern "C" void kernel_launch(void* const* d_in, const int* in_sizes, int n_in,
                              void* d_out, int out_size, void* d_ws, size_t ws_size,
                              hipStream_t stream) {
    const float* x   = (const float*)d_in[0];
    const float* Wih = (const float*)d_in[1];
    const float* Whh = (const float*)d_in[2];
    const float* bih = (const float*)d_in[3];
    const float* bhh = (const float*)d_in[4];
    const float* Wo  = (const float*)d_in[5];
    const float* bo  = (const float*)d_in[6];

    float* outputs = (float*)d_out;                      // [64][2048][1]
    float* hiddens = (float*)d_out + (size_t)BB * TT;    // [64][2048][256]

    // Workspace: Wt (393216 B) | Wih f16 (196608 B) | gi f16 (201326592 B)
    unsigned int* Wt = (unsigned int*)d_ws;
    _Float16* Wh = (_Float16*)((char*)d_ws + 128 * GG * sizeof(unsigned int));
    _Float16* gi = (_Float16*)((char*)Wh + (size_t)GG * II * sizeof(_Float16));

    conv_whh<<<dim3(98304 / 256), dim3(256), 0, stream>>>(Whh, Wt);
    conv_wih<<<dim3(98304 / 256), dim3(256), 0, stream>>>(Wih, Wh);
    gi_mfma <<<dim3((BB * TT) / 64, GG / 64), dim3(256), 0, stream>>>(x, Wh, bih, gi);
    gru_rec <<<dim3(BB), dim3(1024), 0, stream>>>(Wt, gi, bhh, hiddens);
    out_proj<<<dim3((BB * TT) / 4), dim3(256), 0, stream>>>(hiddens, Wo, bo, outputs);
}